// Round 8
// baseline (751.995 us; speedup 1.0000x reference)
//
#include <hip/hip_runtime.h>
#include <math.h>

// Problem constants
#define BATCH   64
#define SAMP    32
#define SIGLEN  19530            // sum_{k=1..6} 5^k
#define NROWS   (BATCH * SAMP)   // 2048
#define NBISECT 40               // fp32 bisection on [0,2] fixed point after ~30 iters == 100

// Level boundaries (element index): level k occupies [LB[k-1], LB[k])
// LB = {0, 5, 30, 155, 780, 3905, 19530}

typedef float f32x4 __attribute__((ext_vector_type(4)));

// ---------------------------------------------------------------------------
// Single-pass kernel: one block per (b,s) row.
//  1) stream the row ONCE (NT float4), retaining all elements in registers
//     while accumulating the 6 per-level sums of x^2
//  2) block reduction + bisection -> weights w[m] = root^(m+1)/SAMP
//  3) scale retained registers, unsafeAtomicAdd (HW global_atomic_add_f32,
//     fire-and-forget) into out[b,:]
// Eliminates the entire second 160 MB read of the two-kernel structure.
// XCD affinity: blockIdx%8 keeps all 32 samples of a batch on one XCD
// (perf heuristic only; correctness independent of placement).
// ---------------------------------------------------------------------------
__global__ __launch_bounds__(256, 4) void es_onepass_kernel(
        const float* __restrict__ x, float* __restrict__ out) {
    const int blk = blockIdx.x;              // 0..2047
    const int m   = blk & 7;                 // heuristic XCD id
    const int h   = blk >> 3;                // 0..255
    const int bat = m * 8 + (h >> 5);        // batch 0..63 (8 per XCD)
    const int s   = h & 31;                  // sample 0..31
    const int r   = bat * SAMP + s;          // row id
    const int t   = threadIdx.x;
    const float* __restrict__ row = x + (size_t)r * SIGLEN;

    float a1 = 0.f, a2 = 0.f, a3 = 0.f, a4 = 0.f, a5 = 0.f, a6 = 0.f;

    // ---- edges, retained in scalars ----
    // [0,155): one scalar for t<155 (levels 1/2/3)
    float eT = 0.f;
    if (t < 155) {
        eT = row[t];
        const float v = eT * eT;
        if (t < 5) a1 += v; else if (t < 30) a2 += v; else a3 += v;
    }
    // [155,780) level 4: cols 155+t, 411+t, 667+t(t<113)
    float e1 = row[155 + t]; a4 += e1 * e1;
    float e2 = row[411 + t]; a4 += e2 * e2;
    float e3 = 0.f;
    if (t < 113) { e3 = row[667 + t]; a4 += e3 * e3; }

    // ---- alignment specials (row base elem r*19530 % 4 == 2*(r&1)) ----
    const int head = (r & 1) ? 2 : 0;
    float sp0 = 0.f, sp1 = 0.f;              // t==0 pair
    float sq0 = 0.f, sq1 = 0.f, sq2 = 0.f, sq3 = 0.f;  // t==64 straddle quad
    if (head) {
        if (t == 0)  { sp0 = row[780];  sp1 = row[781];
                       a5 += sp0*sp0 + sp1*sp1; }
        if (t == 64) { sq0 = row[3902]; sq1 = row[3903]; sq2 = row[3904]; sq3 = row[3905];
                       a5 += sq0*sq0 + sq1*sq1 + sq2*sq2; a6 += sq3*sq3; }
    } else {
        if (t == 0)  { sp0 = row[19528]; sp1 = row[19529];
                       a6 += sp0*sp0 + sp1*sp1; }
        if (t == 64) { sq0 = row[3904]; sq1 = row[3905]; sq2 = row[3906]; sq3 = row[3907];
                       a5 += sq0*sq0; a6 += sq1*sq1 + sq2*sq2 + sq3*sq3; }
    }

    // ---- main f4 spans (16B-aligned; r5-proven geometry) ----
    const int cA = 780 + head;               // first col of level-5 f4 span
    const int cB = head ? 3906 : 3908;       // first col of level-6 f4 span
    const int Q5 = head ? 780  : 781;        // f4 count, level-5 span
    const int Q6 = head ? 3906 : 3905;       // f4 count, level-6 span
    const f32x4* __restrict__ pA = (const f32x4*)(row + cA);
    const f32x4* __restrict__ pB = (const f32x4*)(row + cB);

    // Level-5 slots: q = t+256k. k=0..2 always valid (767 < 780); k=3 cond.
    f32x4 va0, va1, va2, va3 = {0.f, 0.f, 0.f, 0.f};
#define DOT4(v) ((v).x*(v).x + (v).y*(v).y + (v).z*(v).z + (v).w*(v).w)
    va0 = __builtin_nontemporal_load(pA + t);        a5 += DOT4(va0);
    va1 = __builtin_nontemporal_load(pA + t + 256);  a5 += DOT4(va1);
    va2 = __builtin_nontemporal_load(pA + t + 512);  a5 += DOT4(va2);
    const bool vA3 = (t + 768) < Q5;
    if (vA3) { va3 = __builtin_nontemporal_load(pA + t + 768); a5 += DOT4(va3); }

    // Level-6 slots: k=0..14 always valid (3839 < 3905); k=15 cond.
    f32x4 vb0,vb1,vb2,vb3,vb4,vb5,vb6,vb7,vb8,vb9,vb10,vb11,vb12,vb13,vb14;
    f32x4 vb15 = {0.f, 0.f, 0.f, 0.f};
#define LOADB(k) { vb##k = __builtin_nontemporal_load(pB + t + 256*(k)); a6 += DOT4(vb##k); }
    LOADB(0)  LOADB(1)  LOADB(2)  LOADB(3)  LOADB(4)
    LOADB(5)  LOADB(6)  LOADB(7)  LOADB(8)  LOADB(9)
    LOADB(10) LOADB(11) LOADB(12) LOADB(13) LOADB(14)
#undef LOADB
    const bool vB15 = (t + 3840) < Q6;
    if (vB15) { vb15 = __builtin_nontemporal_load(pB + t + 3840); a6 += DOT4(vb15); }
#undef DOT4

    // ---- block reduction: 64-lane butterfly, then cross-wave via LDS ----
    #pragma unroll
    for (int off = 32; off > 0; off >>= 1) {
        a1 += __shfl_xor(a1, off); a2 += __shfl_xor(a2, off);
        a3 += __shfl_xor(a3, off); a4 += __shfl_xor(a4, off);
        a5 += __shfl_xor(a5, off); a6 += __shfl_xor(a6, off);
    }
    __shared__ float red[4][6];
    __shared__ float wlds[6];
    const int wave = t >> 6, lane = t & 63;
    if (lane == 0) {
        red[wave][0] = a1; red[wave][1] = a2; red[wave][2] = a3;
        red[wave][3] = a4; red[wave][4] = a5; red[wave][5] = a6;
    }
    __syncthreads();

    if (t == 0) {
        float s1 = 0.f, s2 = 0.f, s3 = 0.f, s4 = 0.f, s5 = 0.f, s6 = 0.f;
        #pragma unroll
        for (int w = 0; w < 4; ++w) {
            s1 += red[w][0]; s2 += red[w][1]; s3 += red[w][2];
            s4 += red[w][3]; s5 += red[w][4]; s6 += red[w][5];
        }
        const float total = s1 + s2 + s3 + s4 + s5 + s6;
        const float nq  = 1.0f + total;
        const float phi = (nq > 4.0f) ? (8.0f - 16.0f / nq) : nq;  // C=4,a=1
        const float c0  = 1.0f - phi;
        const bool  fin = isfinite(c0) && isfinite(total);

        float lo = 0.0f, hi = 2.0f;
        #pragma unroll 4
        for (int i = 0; i < NBISECT; ++i) {
            const float mid = 0.5f * (lo + hi);
            const float u = mid * mid;
            const float pv = ((((((s6*u + s5)*u + s4)*u + s3)*u + s2)*u + s1)*u) + c0;
            const bool neg = pv < 0.0f;               // NaN -> false (matches jnp.where)
            lo = neg ? mid : lo;
            hi = neg ? hi : mid;
        }
        float root = 0.5f * (lo + hi);
        if (!fin) root = 0.0f;
        root = fminf(root, 1.0f);

        const float inv = 1.0f / SAMP;                // fold the mean into weights
        float w1 = root, w2 = w1*root, w3 = w2*root, w4 = w3*root, w5 = w4*root, w6 = w5*root;
        wlds[0] = w1 * inv; wlds[1] = w2 * inv; wlds[2] = w3 * inv;
        wlds[3] = w4 * inv; wlds[4] = w5 * inv; wlds[5] = w6 * inv;
    }
    __syncthreads();

    const float w4f = wlds[3], w5f = wlds[4], w6f = wlds[5];
    float* __restrict__ ob = out + (size_t)bat * SIGLEN;

    // ---- scatter-add retained registers (HW f32 atomics, non-returning) ----
    if (t < 155) {
        const float wE = (t < 5) ? wlds[0] : ((t < 30) ? wlds[1] : wlds[2]);
        unsafeAtomicAdd(&ob[t], eT * wE);
    }
    unsafeAtomicAdd(&ob[155 + t], e1 * w4f);
    unsafeAtomicAdd(&ob[411 + t], e2 * w4f);
    if (t < 113) unsafeAtomicAdd(&ob[667 + t], e3 * w4f);

    if (head) {
        if (t == 0)  { unsafeAtomicAdd(&ob[780],  sp0 * w5f);
                       unsafeAtomicAdd(&ob[781],  sp1 * w5f); }
        if (t == 64) { unsafeAtomicAdd(&ob[3902], sq0 * w5f);
                       unsafeAtomicAdd(&ob[3903], sq1 * w5f);
                       unsafeAtomicAdd(&ob[3904], sq2 * w5f);
                       unsafeAtomicAdd(&ob[3905], sq3 * w6f); }
    } else {
        if (t == 0)  { unsafeAtomicAdd(&ob[19528], sp0 * w6f);
                       unsafeAtomicAdd(&ob[19529], sp1 * w6f); }
        if (t == 64) { unsafeAtomicAdd(&ob[3904], sq0 * w5f);
                       unsafeAtomicAdd(&ob[3905], sq1 * w6f);
                       unsafeAtomicAdd(&ob[3906], sq2 * w6f);
                       unsafeAtomicAdd(&ob[3907], sq3 * w6f); }
    }

#define ATOM4(base, v, wf) { \
        unsafeAtomicAdd(&ob[(base) + 0], (v).x * (wf)); \
        unsafeAtomicAdd(&ob[(base) + 1], (v).y * (wf)); \
        unsafeAtomicAdd(&ob[(base) + 2], (v).z * (wf)); \
        unsafeAtomicAdd(&ob[(base) + 3], (v).w * (wf)); }

    ATOM4(cA + 4*t,          va0, w5f)
    ATOM4(cA + 4*(t + 256),  va1, w5f)
    ATOM4(cA + 4*(t + 512),  va2, w5f)
    if (vA3) ATOM4(cA + 4*(t + 768), va3, w5f)

#define ATOMB(k) ATOM4(cB + 4*(t + 256*(k)), vb##k, w6f)
    ATOMB(0)  ATOMB(1)  ATOMB(2)  ATOMB(3)  ATOMB(4)
    ATOMB(5)  ATOMB(6)  ATOMB(7)  ATOMB(8)  ATOMB(9)
    ATOMB(10) ATOMB(11) ATOMB(12) ATOMB(13) ATOMB(14)
    if (vB15) ATOMB(15)
#undef ATOMB
#undef ATOM4
}

extern "C" void kernel_launch(void* const* d_in, const int* in_sizes, int n_in,
                              void* d_out, int out_size, void* d_ws, size_t ws_size,
                              hipStream_t stream) {
    const float* x = (const float*)d_in[0];   // [64,32,19530] fp32
    float* out = (float*)d_out;               // [64,19530] fp32
    (void)d_ws; (void)ws_size;                // workspace unused

    // out must be zero before scatter-accumulation (async memset: capture-legal)
    hipMemsetAsync(out, 0, (size_t)out_size, stream);
    es_onepass_kernel<<<NROWS, 256, 0, stream>>>(x, out);
}